// Round 7
// baseline (427.514 us; speedup 1.0000x reference)
//
#include <hip/hip_runtime.h>

#define HW    262144      // 512*512
#define HW4   65536       // HW/4
#define NPIX  2097152     // 8*512*512
#define NG4   (NPIX / 4)  // float4 pixel-groups
#define NBLK  (NG4 / 256) // 2048 blocks, one group per thread
#define CNEW  21
#define COLD  16

// Single kernel, single pass:
//   loss_sum = macc + sum_{c=1..15, c absent} T_c
// T_c accumulated unconditionally; presence bits OR-reduced from masks in the
// same pass; gate applied by the last block to finish (counter + fences).
// float4 loads (16 B/lane), uniform channel order across blocks (convoy ->
// DRAM row locality; R5 showed breaking it costs 2.5x).
__global__ __launch_bounds__(256)
void lgod_main(const float4* __restrict__ inp4,   // [8,21,HW4]
               const float4* __restrict__ tgt4,   // [8,16,HW4]
               const int4*   __restrict__ masks4, // [NG4]
               double* __restrict__ accum,        // ws +0
               float*  __restrict__ Tc,           // ws +8  (15 floats)
               unsigned int* __restrict__ pmp,    // ws +68
               unsigned int* __restrict__ counter,// ws +72
               float* __restrict__ out)
{
    const int t   = blockIdx.x * 256 + threadIdx.x;  // 0 .. NG4-1
    const int b   = t >> 16;
    const int hw4 = t & (HW4 - 1);
    const float4* ip = inp4 + (size_t)b * CNEW * HW4 + hw4;
    const float4* tp = tgt4 + (size_t)b * COLD * HW4 + hw4;

    const int4 mv = masks4[t];
    int ma[4] = {mv.x, mv.y, mv.z, mv.w};
    unsigned int pbits = 0;
    int mm[4];
    #pragma unroll
    for (int j = 0; j < 4; ++j) {
        if (ma[j] >= 1 && ma[j] < CNEW) pbits |= (1u << ma[j]);
        mm[j] = (ma[j] == 0 || ma[j] == 255) ? 0 : ma[j];
    }

    // ---- input sweep: se, vm, keep channels 1..15 ----
    float ikeep[15][4];
    float se[4], vm[4];
    {
        float4 iv = ip[0];
        float ia[4] = {iv.x, iv.y, iv.z, iv.w};
        #pragma unroll
        for (int j = 0; j < 4; ++j) { se[j] = __expf(ia[j]); vm[j] = ia[j]; }
    }
    #pragma unroll
    for (int c = 1; c < CNEW; ++c) {
        float4 iv = ip[(size_t)c * HW4];
        float ia[4] = {iv.x, iv.y, iv.z, iv.w};
        #pragma unroll
        for (int j = 0; j < 4; ++j) {
            if (c < COLD) ikeep[c - 1][j] = ia[j];
            se[j] += __expf(ia[j]);
            vm[j] = (c == mm[j]) ? ia[j] : vm[j];
        }
    }

    // ---- target sweep: e[c], st ----
    float e[COLD][4];
    float st[4] = {0, 0, 0, 0};
    #pragma unroll
    for (int c = 0; c < COLD; ++c) {
        float4 tv = tp[(size_t)c * HW4];
        float ta[4] = {tv.x, tv.y, tv.z, tv.w};
        #pragma unroll
        for (int j = 0; j < 4; ++j) {
            e[c][j] = __expf(ta[j]);
            st[j] += e[c][j];
        }
    }

    // ---- per-pixel finalize math ----
    float macc = 0.f;
    float tacc[15];
    #pragma unroll
    for (int i = 0; i < 15; ++i) tacc[i] = 0.f;
    #pragma unroll
    for (int j = 0; j < 4; ++j) {
        const float lse = __logf(se[j]);
        const float inv = 1.0f / st[j];
        if (ma[j] < CNEW || ma[j] == 255)
            macc += (vm[j] - lse) * e[0][j] * inv;
        #pragma unroll
        for (int c = 1; c < COLD; ++c)
            tacc[c - 1] += (ikeep[c - 1][j] - lse) * e[c][j] * inv;
    }

    // ---- reductions: wave butterfly -> LDS -> thread0 atomics ----
    #pragma unroll
    for (int off = 32; off; off >>= 1) macc += __shfl_down(macc, off);
    #pragma unroll
    for (int i = 0; i < 15; ++i) {
        #pragma unroll
        for (int off = 32; off; off >>= 1) tacc[i] += __shfl_down(tacc[i], off);
    }
    #pragma unroll
    for (int off = 32; off; off >>= 1) pbits |= __shfl_down(pbits, off);

    __shared__ float s_m[4];
    __shared__ float s_t[4][15];
    __shared__ unsigned int s_p;
    if (threadIdx.x == 0) s_p = 0;
    __syncthreads();
    const int wid = threadIdx.x >> 6;
    if ((threadIdx.x & 63) == 0) {
        s_m[wid] = macc;
        #pragma unroll
        for (int i = 0; i < 15; ++i) s_t[wid][i] = tacc[i];
        if (pbits) atomicOr(&s_p, pbits);
    }
    __syncthreads();

    if (threadIdx.x == 0) {
        atomicAdd(accum, (double)(s_m[0] + s_m[1] + s_m[2] + s_m[3]));
        #pragma unroll
        for (int i = 0; i < 15; ++i)
            atomicAdd(&Tc[i], s_t[0][i] + s_t[1][i] + s_t[2][i] + s_t[3][i]);
        if (s_p) atomicOr(pmp, s_p);
        __threadfence();
        const unsigned int done = atomicAdd(counter, 1u);
        if (done == NBLK - 1) {              // last block finishes the scalar
            __threadfence();
            double v = atomicAdd(accum, 0.0);
            const unsigned int pm = atomicOr(pmp, 0u);
            #pragma unroll
            for (int c = 1; c < COLD; ++c)
                if (!((pm >> c) & 1u))
                    v += (double)atomicAdd(&Tc[c - 1], 0.f);
            out[0] = (float)(-v / ((double)CNEW * (double)NPIX));
        }
    }
}

extern "C" void kernel_launch(void* const* d_in, const int* in_sizes, int n_in,
                              void* d_out, int out_size, void* d_ws, size_t ws_size,
                              hipStream_t stream) {
    const float4* inp4  = (const float4*)d_in[0];
    const float4* tgt4  = (const float4*)d_in[1];
    const int4*   masks = (const int4*)d_in[2];
    float* out = (float*)d_out;

    double* accum         = (double*)d_ws;                       // +0, 8 B
    float*  Tc            = (float*)((char*)d_ws + 8);           // +8, 60 B
    unsigned int* pm      = (unsigned int*)((char*)d_ws + 68);   // +68, 4 B
    unsigned int* counter = (unsigned int*)((char*)d_ws + 72);   // +72, 4 B

    hipMemsetAsync(d_ws, 0, 128, stream);
    lgod_main<<<NBLK, 256, 0, stream>>>(inp4, tgt4, masks,
                                        accum, Tc, pm, counter, out);
    (void)out_size; (void)ws_size; (void)n_in; (void)in_sizes;
}

// Round 8
// 181.330 us; speedup vs baseline: 2.3577x; 2.3577x over previous
//
#include <hip/hip_runtime.h>

#define HW    262144      // 512*512
#define HW4   65536       // HW/4
#define NPIX  2097152     // 8*512*512
#define NG4   (NPIX / 4)  // float4 pixel-groups
#define NBLK  (NG4 / 256) // 2048
#define CNEW  21
#define COLD  16

// ---------- pass 1: bitmask of classes present in masks ----------
__global__ __launch_bounds__(256)
void lgod_present_scan(const int4* __restrict__ m4,
                       unsigned int* __restrict__ pm) {
    const int p = blockIdx.x * 256 + threadIdx.x;   // one int4 per thread
    int4 v = m4[p];
    unsigned int local = 0;
    if (v.x >= 1 && v.x < CNEW) local |= (1u << v.x);
    if (v.y >= 1 && v.y < CNEW) local |= (1u << v.y);
    if (v.z >= 1 && v.z < CNEW) local |= (1u << v.z);
    if (v.w >= 1 && v.w < CNEW) local |= (1u << v.w);
    #pragma unroll
    for (int off = 32; off; off >>= 1) local |= __shfl_down(local, off);
    __shared__ unsigned int sm;
    if (threadIdx.x == 0) sm = 0;
    __syncthreads();
    if ((threadIdx.x & 63) == 0 && local) atomicOr(&sm, local);
    __syncthreads();
    if (threadIdx.x == 0 && sm) atomicOr(pm, sm);
}

// ---------- pass 2: fused loss (R2 consume-on-load structure) + last-block finalize ----------
__global__ __launch_bounds__(256)
void lgod_main(const float4* __restrict__ inp4,   // [8,21,HW4]
               const float4* __restrict__ tgt4,   // [8,16,HW4]
               const int4*   __restrict__ masks4, // [NG4]
               const unsigned int* __restrict__ pm_p,
               double* __restrict__ accum,
               unsigned int* __restrict__ counter,
               float* __restrict__ out)
{
    const unsigned int pm = *pm_p;
    const int t   = blockIdx.x * 256 + threadIdx.x;  // 0 .. NG4-1
    const int b   = t >> 16;
    const int hw4 = t & (HW4 - 1);
    const float4* ip = inp4 + (size_t)b * CNEW * HW4 + hw4;
    const float4* tp = tgt4 + (size_t)b * COLD * HW4 + hw4;

    const int4 mv = masks4[t];
    int ma[4] = {mv.x, mv.y, mv.z, mv.w};
    int mm[4];
    #pragma unroll
    for (int j = 0; j < 4; ++j)
        mm[j] = (ma[j] == 0 || ma[j] == 255) ? 0 : ma[j];

    float se[4] = {0,0,0,0};   // sum exp(inputs)
    float st[4] = {0,0,0,0};   // sum exp(targets)
    float P[4]  = {0,0,0,0};   // sum_absent in[c]*exp(t[c])
    float Q[4]  = {0,0,0,0};   // sum_absent exp(t[c])
    float t0e[4];              // exp(t[0])
    float vm[4];               // in[mm]

    #pragma unroll
    for (int c = 0; c < COLD; ++c) {
        float4 iv = ip[(size_t)c * HW4];
        float4 tv = tp[(size_t)c * HW4];
        float ia[4] = {iv.x, iv.y, iv.z, iv.w};
        float ta[4] = {tv.x, tv.y, tv.z, tv.w};
        const bool absent = (c >= 1) && !((pm >> c) & 1u);  // wave-uniform
        #pragma unroll
        for (int j = 0; j < 4; ++j) {
            float e = __expf(ta[j]);
            st[j] += e;
            if (c == 0) t0e[j] = e;
            if (absent) { P[j] += ia[j] * e; Q[j] += e; }
            se[j] += __expf(ia[j]);
            if (c == 0) vm[j] = ia[j];
            else        vm[j] = (c == mm[j]) ? ia[j] : vm[j];
        }
    }
    #pragma unroll
    for (int c = COLD; c < CNEW; ++c) {
        float4 iv = ip[(size_t)c * HW4];
        float ia[4] = {iv.x, iv.y, iv.z, iv.w};
        #pragma unroll
        for (int j = 0; j < 4; ++j) {
            se[j] += __expf(ia[j]);
            vm[j] = (c == mm[j]) ? ia[j] : vm[j];
        }
    }

    float acc = 0.f;
    #pragma unroll
    for (int j = 0; j < 4; ++j) {
        float lse = __logf(se[j]);
        float inv = 1.0f / st[j];
        float S = 0.f;
        if (ma[j] < CNEW || ma[j] == 255)     // valid label -> out[mm]*labels0
            S = (vm[j] - lse) * t0e[j];
        S += P[j] - lse * Q[j];               // absent-class channels (0 if none)
        acc += S * inv;
    }

    // wave reduce -> block reduce -> one double atomic -> last block finalizes
    #pragma unroll
    for (int off = 32; off; off >>= 1) acc += __shfl_down(acc, off);
    __shared__ float warp_s[4];
    const int wid = threadIdx.x >> 6;
    if ((threadIdx.x & 63) == 0) warp_s[wid] = acc;
    __syncthreads();
    if (threadIdx.x == 0) {
        float tot = warp_s[0] + warp_s[1] + warp_s[2] + warp_s[3];
        atomicAdd(accum, (double)tot);
        __threadfence();
        const unsigned int done = atomicAdd(counter, 1u);
        if (done == NBLK - 1) {
            __threadfence();
            double v = atomicAdd(accum, 0.0);   // coherent read of final sum
            out[0] = (float)(-v / ((double)CNEW * (double)NPIX));
        }
    }
}

extern "C" void kernel_launch(void* const* d_in, const int* in_sizes, int n_in,
                              void* d_out, int out_size, void* d_ws, size_t ws_size,
                              hipStream_t stream) {
    const float4* inp4  = (const float4*)d_in[0];
    const float4* tgt4  = (const float4*)d_in[1];
    const int4*   masks = (const int4*)d_in[2];
    float* out = (float*)d_out;

    double* accum         = (double*)d_ws;                       // +0, 8 B
    unsigned int* pm      = (unsigned int*)((char*)d_ws + 8);    // +8, 4 B
    unsigned int* counter = (unsigned int*)((char*)d_ws + 12);   // +12, 4 B

    hipMemsetAsync(d_ws, 0, 16, stream);
    lgod_present_scan<<<NBLK, 256, 0, stream>>>(masks, pm);
    lgod_main<<<NBLK, 256, 0, stream>>>(inp4, tgt4, masks, pm,
                                        accum, counter, out);
    (void)out_size; (void)ws_size; (void)n_in; (void)in_sizes;
}

// Round 9
// 87.729 us; speedup vs baseline: 4.8731x; 2.0669x over previous
//
#include <hip/hip_runtime.h>

#define HW    262144      // 512*512
#define HW2   131072      // HW/2
#define NPIX  2097152     // 8*512*512
#define NG2   (NPIX / 2)  // float2 pixel-groups
#define NBLK2 (NG2 / 256) // 4096
#define CNEW  21
#define COLD  16

// ---------- pass 1: bitmask of classes present in masks ----------
__global__ __launch_bounds__(256)
void lgod_present_scan(const int4* __restrict__ m4,
                       unsigned int* __restrict__ pm) {
    unsigned int local = 0;
    const int stride = gridDim.x * blockDim.x;
    for (int p = blockIdx.x * blockDim.x + threadIdx.x; p < NPIX / 4; p += stride) {
        int4 v = m4[p];
        if (v.x >= 1 && v.x < CNEW) local |= (1u << v.x);
        if (v.y >= 1 && v.y < CNEW) local |= (1u << v.y);
        if (v.z >= 1 && v.z < CNEW) local |= (1u << v.z);
        if (v.w >= 1 && v.w < CNEW) local |= (1u << v.w);
    }
    #pragma unroll
    for (int off = 32; off; off >>= 1) local |= __shfl_down(local, off);
    __shared__ unsigned int sm;
    if (threadIdx.x == 0) sm = 0;
    __syncthreads();
    if ((threadIdx.x & 63) == 0 && local) atomicOr(&sm, local);
    __syncthreads();
    if (threadIdx.x == 0 && sm) atomicOr(pm, sm);
}

// ---------- pass 2: fused loss — float2, 2 px/thread, uniform channel order ----------
// Isolated probe of the wave-parallelism lever: ~48 VGPR -> ~46% occupancy,
// 2.5x the resident waves of the float4 variant, 8 B/lane loads.
// No rotation (R5), no fused finalize (R8) — both proven toxic.
__global__ __launch_bounds__(256)
void lgod_main(const float2* __restrict__ inp2,   // [8,21,HW2]
               const float2* __restrict__ tgt2,   // [8,16,HW2]
               const int2*   __restrict__ masks2, // [NG2]
               const unsigned int* __restrict__ pm_p,
               double* __restrict__ accum)
{
    const unsigned int pm = *pm_p;
    const int t   = blockIdx.x * 256 + threadIdx.x;  // 0 .. NG2-1
    const int b   = t >> 17;
    const int hw2 = t & (HW2 - 1);
    const float2* ip = inp2 + (size_t)b * CNEW * HW2 + hw2;
    const float2* tp = tgt2 + (size_t)b * COLD * HW2 + hw2;

    const int2 mv = masks2[t];
    int ma[2] = {mv.x, mv.y};
    int mm[2];
    #pragma unroll
    for (int j = 0; j < 2; ++j)
        mm[j] = (ma[j] == 0 || ma[j] == 255) ? 0 : ma[j];

    float se[2] = {0,0};   // sum exp(inputs)
    float st[2] = {0,0};   // sum exp(targets)
    float P[2]  = {0,0};   // sum_absent in[c]*exp(t[c])
    float Q[2]  = {0,0};   // sum_absent exp(t[c])
    float t0e[2];          // exp(t[0])
    float vm[2];           // in[mm]

    #pragma unroll
    for (int c = 0; c < COLD; ++c) {
        float2 iv = ip[(size_t)c * HW2];
        float2 tv = tp[(size_t)c * HW2];
        float ia[2] = {iv.x, iv.y};
        float ta[2] = {tv.x, tv.y};
        const bool absent = (c >= 1) && !((pm >> c) & 1u);  // wave-uniform
        #pragma unroll
        for (int j = 0; j < 2; ++j) {
            float e = __expf(ta[j]);
            st[j] += e;
            if (c == 0) t0e[j] = e;
            if (absent) { P[j] += ia[j] * e; Q[j] += e; }
            se[j] += __expf(ia[j]);
            if (c == 0) vm[j] = ia[j];
            else        vm[j] = (c == mm[j]) ? ia[j] : vm[j];
        }
    }
    #pragma unroll
    for (int c = COLD; c < CNEW; ++c) {
        float2 iv = ip[(size_t)c * HW2];
        float ia[2] = {iv.x, iv.y};
        #pragma unroll
        for (int j = 0; j < 2; ++j) {
            se[j] += __expf(ia[j]);
            vm[j] = (c == mm[j]) ? ia[j] : vm[j];
        }
    }

    float acc = 0.f;
    #pragma unroll
    for (int j = 0; j < 2; ++j) {
        float lse = __logf(se[j]);
        float inv = 1.0f / st[j];
        float S = 0.f;
        if (ma[j] < CNEW || ma[j] == 255)     // valid label -> out[mm]*labels0
            S = (vm[j] - lse) * t0e[j];
        S += P[j] - lse * Q[j];               // absent-class channels (0 if none)
        acc += S * inv;
    }

    // wave reduce -> block reduce -> one double atomic per block
    #pragma unroll
    for (int off = 32; off; off >>= 1) acc += __shfl_down(acc, off);
    __shared__ float warp_s[4];
    const int wid = threadIdx.x >> 6;
    if ((threadIdx.x & 63) == 0) warp_s[wid] = acc;
    __syncthreads();
    if (threadIdx.x == 0) {
        float tot = warp_s[0] + warp_s[1] + warp_s[2] + warp_s[3];
        atomicAdd(accum, (double)tot);
    }
}

// ---------- pass 3: finalize scalar ----------
__global__ void lgod_finalize(const double* __restrict__ accum,
                              float* __restrict__ out) {
    out[0] = (float)(-accum[0] / ((double)CNEW * (double)NPIX));
}

extern "C" void kernel_launch(void* const* d_in, const int* in_sizes, int n_in,
                              void* d_out, int out_size, void* d_ws, size_t ws_size,
                              hipStream_t stream) {
    const float2* inp2  = (const float2*)d_in[0];
    const float2* tgt2  = (const float2*)d_in[1];
    const int*    masks = (const int*)d_in[2];
    float* out = (float*)d_out;

    double* accum    = (double*)d_ws;                       // 8 B
    unsigned int* pm = (unsigned int*)((char*)d_ws + 8);    // 4 B

    hipMemsetAsync(d_ws, 0, 16, stream);
    lgod_present_scan<<<256, 256, 0, stream>>>((const int4*)masks, pm);
    lgod_main<<<NBLK2, 256, 0, stream>>>(inp2, (const float2*)d_in[1],
                                         (const int2*)masks, pm, accum);
    lgod_finalize<<<1, 1, 0, stream>>>(accum, out);
    (void)out_size; (void)ws_size; (void)n_in; (void)in_sizes;
}

// Round 10
// 70.121 us; speedup vs baseline: 6.0968x; 1.2511x over previous
//
#include <hip/hip_runtime.h>

#define HW    262144      // 512*512
#define HW4   65536       // HW/4
#define NPIX  2097152     // 8*512*512
#define CNEW  21
#define COLD  16

// ---------- pass 1: which classes appear in masks (bitmask over 21 classes) ----------
__global__ void lgod_present_scan(const int* __restrict__ masks,
                                  unsigned int* __restrict__ pm) {
    unsigned int local = 0;
    const int4* m4 = (const int4*)masks;
    const int n4 = NPIX / 4;
    const int stride = gridDim.x * blockDim.x;
    for (int p = blockIdx.x * blockDim.x + threadIdx.x; p < n4; p += stride) {
        int4 v = m4[p];
        if (v.x >= 1 && v.x < CNEW) local |= (1u << v.x);
        if (v.y >= 1 && v.y < CNEW) local |= (1u << v.y);
        if (v.z >= 1 && v.z < CNEW) local |= (1u << v.z);
        if (v.w >= 1 && v.w < CNEW) local |= (1u << v.w);
    }
    #pragma unroll
    for (int off = 32; off; off >>= 1) local |= __shfl_down(local, off);
    __shared__ unsigned int sm;
    if (threadIdx.x == 0) sm = 0;
    __syncthreads();
    if ((threadIdx.x & 63) == 0 && local) atomicOr(&sm, local);
    __syncthreads();
    if (threadIdx.x == 0 && sm) atomicOr(pm, sm);
}

// ---------- pass 2: fused online log_softmax x softmax distillation ----------
// Each thread owns 4 consecutive pixels; every channel stream is one dwordx4.
// Max-free softmax (inputs are O(1) normals; exp cannot overflow in f32).
// Best-measured structure (R2: 68.2 us harness); six alternative structures
// (scalar, float2, ILP-burst, grid-stride, rotation, fused-finalize) all tied
// or regressed -> 37-stream memory-pattern plateau.
__global__ __launch_bounds__(256)
void lgod_main(const float4* __restrict__ inp4,   // [8,21,HW/4]
               const float4* __restrict__ tgt4,   // [8,16,HW/4]
               const int4*   __restrict__ masks4, // [NPIX/4]
               const unsigned int* __restrict__ pm_p,
               double* __restrict__ accum) {
    const unsigned int pm = *pm_p;
    const int t   = blockIdx.x * blockDim.x + threadIdx.x;  // 0 .. NPIX/4-1
    const int b   = t >> 16;          // (t*4) / HW
    const int hw4 = t & (HW4 - 1);
    const float4* ip = inp4 + (size_t)b * CNEW * HW4 + hw4;
    const float4* tp = tgt4 + (size_t)b * COLD * HW4 + hw4;

    const int4 mv = masks4[t];
    int ma[4] = {mv.x, mv.y, mv.z, mv.w};
    int mm[4];
    #pragma unroll
    for (int j = 0; j < 4; ++j)
        mm[j] = (ma[j] == 0 || ma[j] == 255) ? 0 : ma[j];

    float se[4] = {0,0,0,0};   // sum exp(inputs)
    float st[4] = {0,0,0,0};   // sum exp(targets)
    float P[4]  = {0,0,0,0};   // sum_absent in[c]*exp(t[c])
    float Q[4]  = {0,0,0,0};   // sum_absent exp(t[c])
    float t0e[4];              // exp(t[0])
    float vm[4];               // in[mm]

    #pragma unroll
    for (int c = 0; c < COLD; ++c) {
        float4 iv = ip[(size_t)c * HW4];
        float4 tv = tp[(size_t)c * HW4];
        float ia[4] = {iv.x, iv.y, iv.z, iv.w};
        float ta[4] = {tv.x, tv.y, tv.z, tv.w};
        const bool absent = (c >= 1) && !((pm >> c) & 1u);  // wave-uniform
        #pragma unroll
        for (int j = 0; j < 4; ++j) {
            float e = __expf(ta[j]);
            st[j] += e;
            if (c == 0) t0e[j] = e;
            if (absent) { P[j] += ia[j] * e; Q[j] += e; }
            se[j] += __expf(ia[j]);
            if (c == 0) vm[j] = ia[j];
            else        vm[j] = (c == mm[j]) ? ia[j] : vm[j];
        }
    }
    #pragma unroll
    for (int c = COLD; c < CNEW; ++c) {
        float4 iv = ip[(size_t)c * HW4];
        float ia[4] = {iv.x, iv.y, iv.z, iv.w};
        #pragma unroll
        for (int j = 0; j < 4; ++j) {
            se[j] += __expf(ia[j]);
            vm[j] = (c == mm[j]) ? ia[j] : vm[j];
        }
    }

    float acc = 0.f;
    #pragma unroll
    for (int j = 0; j < 4; ++j) {
        float lse = __logf(se[j]);
        float inv = 1.0f / st[j];
        float S = 0.f;
        if (ma[j] < CNEW || ma[j] == 255)     // valid label -> out[mm]*labels0
            S = (vm[j] - lse) * t0e[j];
        S += P[j] - lse * Q[j];               // absent-class channels (0 if none)
        acc += S * inv;
    }

    // wave reduce -> block reduce -> one double atomic per block
    #pragma unroll
    for (int off = 32; off; off >>= 1) acc += __shfl_down(acc, off);
    __shared__ float warp_s[4];
    const int wid = threadIdx.x >> 6;
    if ((threadIdx.x & 63) == 0) warp_s[wid] = acc;
    __syncthreads();
    if (threadIdx.x == 0) {
        float tot = warp_s[0] + warp_s[1] + warp_s[2] + warp_s[3];
        atomicAdd(accum, (double)tot);
    }
}

// ---------- pass 3: finalize scalar ----------
__global__ void lgod_finalize(const double* __restrict__ accum,
                              float* __restrict__ out) {
    out[0] = (float)(-accum[0] / ((double)CNEW * (double)NPIX));
}

extern "C" void kernel_launch(void* const* d_in, const int* in_sizes, int n_in,
                              void* d_out, int out_size, void* d_ws, size_t ws_size,
                              hipStream_t stream) {
    const float4* inp4   = (const float4*)d_in[0];
    const float4* tgt4   = (const float4*)d_in[1];
    const int*    masks  = (const int*)d_in[2];
    float* out = (float*)d_out;

    double* accum    = (double*)d_ws;                       // 8 B
    unsigned int* pm = (unsigned int*)((char*)d_ws + 8);    // 4 B

    hipMemsetAsync(d_ws, 0, 16, stream);
    lgod_present_scan<<<256, 256, 0, stream>>>(masks, pm);
    lgod_main<<<NPIX / 4 / 256, 256, 0, stream>>>(inp4, (const float4*)d_in[1],
                                                  (const int4*)masks, pm, accum);
    lgod_finalize<<<1, 1, 0, stream>>>(accum, out);
    (void)out_size; (void)ws_size; (void)n_in; (void)in_sizes;
}